// Round 15
// baseline (30.813 us; speedup 1.0000x reference)
//
#include <hip/hip_runtime.h>

#define F 32
#define Dd 16
#define C 64
#define Kk 8
#define CLIPV (1.0f - 1e-6f)
#define K2 2.8853900817779268f   // 2*log2(e): tanh(z)=1-2/(2^(K2*z)+1)
#define INV2PI 0.15915494309189535f
#define NBLK 1024
#define MT 2               // row-tiles of 64 per block

typedef short v8s __attribute__((ext_vector_type(8)));
typedef float v4f __attribute__((ext_vector_type(4)));
typedef float v2f __attribute__((ext_vector_type(2)));

static __device__ inline unsigned cvtpk(float lo, float hi) {
    unsigned r;
    asm("v_cvt_pk_bf16_f32 %0, %1, %2" : "=v"(r) : "v"(lo), "v"(hi));
    return r;
}

// Forced VOP3P packed-f32 ops
static __device__ inline v2f pk_sub(v2f a, v2f b) {  // a - b
    v2f r;
    asm("v_pk_add_f32 %0, %1, %2 neg_lo:[0,1] neg_hi:[0,1]"
        : "=v"(r) : "v"(a), "v"(b));
    return r;
}
static __device__ inline v2f pk_fma(v2f a, v2f b, v2f c) {  // a*b + c
    v2f r;
    asm("v_pk_fma_f32 %0, %1, %2, %3"
        : "=v"(r) : "v"(a), "v"(b), "v"(c));
    return r;
}

// LDS-only barriers (no vmcnt drain; X/stores stay in flight)
#define WAIT_LGKM() do {                                         \
    asm volatile("s_waitcnt lgkmcnt(0)" ::: "memory");           \
    __builtin_amdgcn_sched_barrier(0);                           \
} while (0)
#define BAR_WRITES() do {                                        \
    asm volatile("s_waitcnt lgkmcnt(0)" ::: "memory");           \
    __builtin_amdgcn_s_barrier();                                \
    asm volatile("" ::: "memory");                               \
} while (0)
#define BAR_READS() do {                                         \
    asm volatile("" ::: "memory");                               \
    __builtin_amdgcn_s_barrier();                                \
    asm volatile("" ::: "memory");                               \
} while (0)

// r15 = r14 + self-tile MFMA before the barrier + entry X prefetch + raw sin/cos
//  - phase-1 feature-major: thread (fe=tid&31, rg=tid>>5) evals feature fe for
//    rows rg*8..+7 => wave wu produces the ENTIRE basis of row-tile t=wu.
//  - self-overlap: after its ds_writes each wave lgkm-drains and immediately
//    MFMAs its own tile (reads only self-written slots) + stores -- 25% of
//    phase-2 runs inside the phase-1 window, before any barrier.
//  - basis LDS 32768 B exactly, swizzle slot=row^(fe&7); bias via MFMA C-in.
__global__ __launch_bounds__(256, 4) void qkan_kernel(
    const float* __restrict__ X,        // [B,32]
    const float* __restrict__ phases,   // [16]
    const float* __restrict__ lcu_w,    // [32,16]
    const float* __restrict__ sscale,   // [32]
    const float* __restrict__ sbias,    // [32]
    const float* __restrict__ coeff,    // [64,32,8]
    const float* __restrict__ kbias,    // [64]
    float* __restrict__ out)            // [B,64]
{
    __shared__ unsigned short s_basis[F * 512];   // 32768 B exactly

    const int tid = threadIdx.x;
    const int lane = tid & 63;
    const int wu = __builtin_amdgcn_readfirstlane(tid >> 6);
    const int h = lane >> 4;
    const int r16 = lane & 15;
    const int fe = tid & 31;   // eval feature
    const int fe7 = fe & 7;
    const int rg = tid >> 5;   // eval row-group (8 rows)

    const int rb0 = blockIdx.x * (MT * 64);

    // ---- X prefetch for BOTH tiles at entry (latency hides under fold) ----
    float xq[8], xn[8];
    {
        const float* xp0 = X + (size_t)(rb0 + rg * 8) * F + fe;
        const float* xp1 = xp0 + (size_t)64 * F;
#pragma unroll
        for (int m = 0; m < 8; ++m) xq[m] = xp0[m * F];
#pragma unroll
        for (int m = 0; m < 8; ++m) xn[m] = xp1[m * F];
    }

    // ---- fold Clenshaw table for feature fe into VGPRs ----
    // K2*z(x) = sum_d a_d T_d(x) + sqrt(1-x^2) * sum_d b_d U_{d-1}(x) + fbias
    v2f cc[16];
    float fbias;
    {
        const float* lwf = lcu_w + fe * Dd;
        float wv[16];
        float asum = 0.f;
#pragma unroll
        for (int d = 0; d < Dd; ++d) {
            wv[d] = lwf[d];
            asum += fabsf(wv[d]);
        }
        const float sc = K2 * sscale[fe] / (asum + 1e-6f);
#pragma unroll
        for (int d = 0; d < Dd; ++d) {
            // raw HW sin/cos (input in revolutions; |phase|/2pi < ~0.1)
            const float pr = phases[d] * INV2PI;
            float sp, cp;
            asm("v_sin_f32 %0, %1" : "=v"(sp) : "v"(pr));
            asm("v_cos_f32 %0, %1" : "=v"(cp) : "v"(pr));
            cc[d][0] = sc * wv[d] * cp;    // a_{d+1}
            cc[d][1] = -sc * wv[d] * sp;   // b_{d+1}
        }
        fbias = K2 * sbias[fe];
    }

    // ---- B fragments: wave wu owns classes [16wu,16wu+16) ----
    // MFMA step q, lane quarter h, regs j hold phys kappa=(4q+h)*8+j,
    // i.e. f=4q+h, cheb-k=j (same lane<->k map on A and B => K-perm invariant)
    v8s Bfr[8];
    const int cidx = wu * 16 + r16;
#pragma unroll
    for (int q = 0; q < 8; ++q) {
        const float* gp = coeff + ((size_t)(cidx * F + 4 * q + h) * Kk);
        const float4 g0 = *reinterpret_cast<const float4*>(gp);
        const float4 g1 = *reinterpret_cast<const float4*>(gp + 4);
        union { unsigned u[4]; v8s v; } bb;
        bb.u[0] = cvtpk(g0.x, g0.y);
        bb.u[1] = cvtpk(g0.z, g0.w);
        bb.u[2] = cvtpk(g1.x, g1.y);
        bb.u[3] = cvtpk(g1.z, g1.w);
        Bfr[q] = bb.v;
    }
    const float biasreg = kbias[cidx];

#pragma unroll
    for (int mt = 0; mt < MT; ++mt) {
        const int row_base = rb0 + mt * 64;
        if (mt) BAR_READS();  // prev phase-2 LDS reads all consumed; no VMEM drain

        // ---- phase 1: 8 independent row-evals of feature fe, table in VGPRs ----
        // swizzled write slot = row ^ fe7  (row = rg*8+m -> rg*8 + (m^fe7))
#pragma unroll
        for (int m = 0; m < 8; ++m) {
            const float x = __builtin_amdgcn_fmed3f(mt ? xn[m] : xq[m], -CLIPV, CLIPV);
            const float s1 = __builtin_amdgcn_sqrtf(__builtin_fmaf(-x, x, 1.f));
            const float tx = x + x;
            const v2f tx2 = {tx, tx};
            // paired Clenshaw (forced v_pk_*): .x = T-chain, .y = U-chain
            v2f w = {0.f, 0.f}, wp = {0.f, 0.f};
#pragma unroll
            for (int j = 15; j >= 0; --j) {
                const v2f wn = pk_fma(tx2, w, pk_sub(cc[j], wp));
                wp = w;
                w = wn;
            }
            float z = fbias - wp[0];
            z = __builtin_fmaf(x, w[0], z);
            z = __builtin_fmaf(s1, w[1], z);
            // tanh via exp2 (K2 pre-folded): t = 1 - 2/(2^z + 1)
            float e;
            asm("v_exp_f32 %0, %1" : "=v"(e) : "v"(z));
            const float rr = __builtin_amdgcn_rcpf(e + 1.f);
            const float t = __builtin_fmaf(-2.f, rr, 1.f);
            // Chebyshev basis T_0..T_7 -> one b128 LDS write (swizzled slot)
            const float t2 = t + t;
            const float b1 = t;
            const float b2 = t2 * b1 - 1.f;
            const float b3 = t2 * b2 - b1;
            const float b4 = t2 * b3 - b2;
            const float b5 = t2 * b4 - b3;
            const float b6 = t2 * b5 - b4;
            const float b7 = t2 * b6 - b5;
            uint4 pk;
            pk.x = cvtpk(1.f, b1);
            pk.y = cvtpk(b2, b3);
            pk.z = cvtpk(b4, b5);
            pk.w = cvtpk(b6, b7);
            *reinterpret_cast<uint4*>(
                &s_basis[fe * 512 + rg * 64 + ((m ^ fe7) << 3)]) = pk;
        }

        // ---- self-tile MFMA (t = wu): reads ONLY this wave's own writes ----
        WAIT_LGKM();
        {
            const int s0 = ((wu * 16 + r16) ^ h) << 3;
            v4f acc = {biasreg, biasreg, biasreg, biasreg};
#pragma unroll
            for (int q = 0; q < 8; ++q) {
                const int idx = (4 * q + h) * 512 + (s0 ^ ((q & 1) << 5));
                const v8s a = *reinterpret_cast<const v8s*>(&s_basis[idx]);
                acc = __builtin_amdgcn_mfma_f32_16x16x32_bf16(a, Bfr[q], acc, 0, 0, 0);
            }
            const int row0 = row_base + wu * 16 + h * 4;
#pragma unroll
            for (int i = 0; i < 4; ++i) {
                out[(size_t)(row0 + i) * C + cidx] = acc[i];
            }
        }
        BAR_WRITES();  // all waves' writes visible; X/stores stay in flight

        // ---- remaining 3 row-tiles: t = (wu+1..3)&3 ----
#pragma unroll
        for (int k = 1; k < 4; ++k) {
            const int t = (wu + k) & 3;
            const int s0 = ((t * 16 + r16) ^ h) << 3;
            v4f acc = {biasreg, biasreg, biasreg, biasreg};
#pragma unroll
            for (int q = 0; q < 8; ++q) {
                const int idx = (4 * q + h) * 512 + (s0 ^ ((q & 1) << 5));
                const v8s a = *reinterpret_cast<const v8s*>(&s_basis[idx]);
                acc = __builtin_amdgcn_mfma_f32_16x16x32_bf16(a, Bfr[q], acc, 0, 0, 0);
            }
            const int row0 = row_base + t * 16 + h * 4;
#pragma unroll
            for (int i = 0; i < 4; ++i) {
                out[(size_t)(row0 + i) * C + cidx] = acc[i];
            }
        }
    }
}

extern "C" void kernel_launch(void* const* d_in, const int* in_sizes, int n_in,
                              void* d_out, int out_size, void* d_ws, size_t ws_size,
                              hipStream_t stream) {
    const float* X  = (const float*)d_in[0];
    const float* ph = (const float*)d_in[1];
    const float* lw = (const float*)d_in[2];
    const float* ss = (const float*)d_in[3];
    const float* sb = (const float*)d_in[4];
    const float* kc = (const float*)d_in[5];
    const float* kb = (const float*)d_in[6];
    float* out = (float*)d_out;
    qkan_kernel<<<dim3(NBLK), dim3(256), 0, stream>>>(X, ph, lw, ss, sb, kc, kb, out);
}

// Round 17
// 25.838 us; speedup vs baseline: 1.1925x; 1.1925x over previous
//
#include <hip/hip_runtime.h>
#include <hip/hip_bf16.h>

#define F 32
#define Dd 16
#define C 64
#define Kk 8
#define CLIPV (1.0f - 1e-6f)
#define K2 2.8853900817779268f  // 2*log2(e): tanh(z)=1-2/(2^(K2*z)+1)
#define NBLK 1024
#define MT 2              // row-tiles of 64 per block

typedef short v8s __attribute__((ext_vector_type(8)));
typedef float v4f __attribute__((ext_vector_type(4)));
typedef float v2f __attribute__((ext_vector_type(2)));

// bf16 pack via native casts: compiler fuses pairs into v_cvt_pk_bf16_f32
// (measured faster than hand-written inline asm -- guide T12/m240).
static __device__ inline unsigned pkbf(float lo, float hi) {
    const unsigned l = __bfloat16_as_ushort(__float2bfloat16(lo));
    const unsigned hh = __bfloat16_as_ushort(__float2bfloat16(hi));
    return l | (hh << 16);
}

// LDS-only barriers: BAR_WRITES waits own ds_writes (lgkmcnt) then s_barrier;
// BAR_READS is a bare s_barrier (phase-2 ds_reads were all consumed by MFMAs).
// Neither drains vmcnt, so X prefetches / output stores stay in flight.
#define BAR_WRITES() do {                                        \
    asm volatile("s_waitcnt lgkmcnt(0)" ::: "memory");           \
    __builtin_amdgcn_s_barrier();                                \
    asm volatile("" ::: "memory");                               \
} while (0)
#define BAR_READS() do {                                         \
    asm volatile("" ::: "memory");                               \
    __builtin_amdgcn_s_barrier();                                \
    asm volatile("" ::: "memory");                               \
} while (0)

// Structure (r17 = r16 with a compilable pkbf):
//  - phase-1 feature-major: thread (fe=tid&31, rg=tid>>5) evaluates feature fe
//    for rows rg*8..rg*8+7; folded Clenshaw table (33 coeffs) lives in VGPRs;
//    Clenshaw pair via __builtin_elementwise_fma on v2f -> v_pk_fma_f32
//  - basis LDS 32768 B exactly, swizzle slot=row^(fe&7)
//  - phase-2: wave wu owns classes [16wu,16wu+16), Bfr in VGPRs; bias via
//    MFMA C-in
__global__ __launch_bounds__(256, 4) void qkan_kernel(
    const float* __restrict__ X,        // [B,32]
    const float* __restrict__ phases,   // [16]
    const float* __restrict__ lcu_w,    // [32,16]
    const float* __restrict__ sscale,   // [32]
    const float* __restrict__ sbias,    // [32]
    const float* __restrict__ coeff,    // [64,32,8]
    const float* __restrict__ kbias,    // [64]
    float* __restrict__ out)            // [B,64]
{
    __shared__ unsigned short s_basis[F * 512];   // 32768 B exactly

    const int tid = threadIdx.x;
    const int lane = tid & 63;
    const int wu = __builtin_amdgcn_readfirstlane(tid >> 6);
    const int h = lane >> 4;
    const int r16 = lane & 15;
    const int fe = tid & 31;   // eval feature
    const int fe7 = fe & 7;
    const int rg = tid >> 5;   // eval row-group (8 rows)

    const int rb0 = blockIdx.x * (MT * 64);

    // ---- X prefetch for tile 0: xq[m] = X[rb0+rg*8+m][fe] (coalesced) ----
    float xq[8];
    {
        const float* xp = X + (size_t)(rb0 + rg * 8) * F + fe;
#pragma unroll
        for (int m = 0; m < 8; ++m) xq[m] = xp[m * F];
    }

    // ---- fold Clenshaw table for feature fe into VGPRs (once per kernel) ----
    // K2*z(x) = sum_d a_d T_d(x) + sqrt(1-x^2) * sum_d b_d U_{d-1}(x) + fbias
    v2f cc[16];
    float fbias;
    {
        const float* lwf = lcu_w + fe * Dd;
        float wv[16];
        float asum = 0.f;
#pragma unroll
        for (int d = 0; d < Dd; ++d) {
            wv[d] = lwf[d];
            asum += fabsf(wv[d]);
        }
        const float sc = K2 * sscale[fe] / (asum + 1e-6f);
#pragma unroll
        for (int d = 0; d < Dd; ++d) {
            float sp, cp;
            __sincosf(phases[d], &sp, &cp);
            cc[d][0] = sc * wv[d] * cp;    // a_{d+1}
            cc[d][1] = -sc * wv[d] * sp;   // b_{d+1}
        }
        fbias = K2 * sbias[fe];
    }

    // ---- B fragments: wave wu owns classes [16wu,16wu+16) ----
    // MFMA step q, lane quarter h, regs j hold phys kappa=(4q+h)*8+j,
    // i.e. f=4q+h, cheb-k=j (same lane<->k map on A and B => K-perm invariant)
    v8s Bfr[8];
    const int cidx = wu * 16 + r16;
#pragma unroll
    for (int q = 0; q < 8; ++q) {
        const float* gp = coeff + ((size_t)(cidx * F + 4 * q + h) * Kk);
        const float4 g0 = *reinterpret_cast<const float4*>(gp);
        const float4 g1 = *reinterpret_cast<const float4*>(gp + 4);
        union { unsigned u[4]; v8s v; } bb;
        bb.u[0] = pkbf(g0.x, g0.y);
        bb.u[1] = pkbf(g0.z, g0.w);
        bb.u[2] = pkbf(g1.x, g1.y);
        bb.u[3] = pkbf(g1.z, g1.w);
        Bfr[q] = bb.v;
    }
    const float biasreg = kbias[cidx];

    for (int mt = 0; mt < MT; ++mt) {
        const int row_base = rb0 + mt * 64;
        if (mt) BAR_READS();  // prev phase-2 LDS reads all consumed; no VMEM drain

        // prefetch next tile's X (stays in flight across the barriers)
        float xn[8];
        if (mt + 1 < MT) {
            const float* xp = X + (size_t)(row_base + 64 + rg * 8) * F + fe;
#pragma unroll
            for (int m = 0; m < 8; ++m) xn[m] = xp[m * F];
        }

        // ---- phase 1: 8 independent row-evals of feature fe, table in VGPRs ----
        // swizzled write slot = row ^ fe7  (row = rg*8+m -> rg*8 + (m^fe7))
#pragma unroll
        for (int m = 0; m < 8; ++m) {
            const float x = __builtin_amdgcn_fmed3f(xq[m], -CLIPV, CLIPV);
            // 1 - x^2 >= ~1.9e-6 after the clip, so raw hardware sqrt is safe
            const float s1 = __builtin_amdgcn_sqrtf(__builtin_fmaf(-x, x, 1.f));
            const float tx = x + x;
            const v2f tx2 = {tx, tx};
            // paired Clenshaw (native packed fma): .x = T-chain, .y = U-chain
            v2f w = {0.f, 0.f}, wp = {0.f, 0.f};
#pragma unroll
            for (int j = 15; j >= 0; --j) {
                const v2f wn = __builtin_elementwise_fma(tx2, w, cc[j] - wp);
                wp = w;
                w = wn;
            }
            float z = fbias - wp[0];
            z = __builtin_fmaf(x, w[0], z);
            z = __builtin_fmaf(s1, w[1], z);
            // tanh via exp2 (K2 pre-folded): t = 1 - 2/(2^z + 1)
            const float e = __builtin_amdgcn_exp2f(z);
            const float rr = __builtin_amdgcn_rcpf(e + 1.f);
            const float t = __builtin_fmaf(-2.f, rr, 1.f);
            // Chebyshev basis T_0..T_7 -> one b128 LDS write (swizzled slot)
            const float t2 = t + t;
            const float b1 = t;
            const float b2 = t2 * b1 - 1.f;
            const float b3 = t2 * b2 - b1;
            const float b4 = t2 * b3 - b2;
            const float b5 = t2 * b4 - b3;
            const float b6 = t2 * b5 - b4;
            const float b7 = t2 * b6 - b5;
            uint4 pk;
            pk.x = pkbf(1.f, b1);
            pk.y = pkbf(b2, b3);
            pk.z = pkbf(b4, b5);
            pk.w = pkbf(b6, b7);
            *reinterpret_cast<uint4*>(
                &s_basis[fe * 512 + rg * 64 + ((m ^ fe7) << 3)]) = pk;
        }
        BAR_WRITES();  // lgkmcnt(0) only: writes visible; X/stores stay in flight

        // ---- phase 2: MFMA, wave wu computes classes [16wu,16wu+16) for 64 rows ----
        // read slot = (t*16+r16) ^ ((4q+h)&7) -> idx = ((v^h)<<3) ^ ((q&1)<<5)
#pragma unroll
        for (int t = 0; t < 4; ++t) {
            const int s0 = ((t * 16 + r16) ^ h) << 3;
            v4f acc = {biasreg, biasreg, biasreg, biasreg};  // bias via MFMA C-in
#pragma unroll
            for (int q = 0; q < 8; ++q) {
                const int idx = (4 * q + h) * 512 + (s0 ^ ((q & 1) << 5));
                const v8s a = *reinterpret_cast<const v8s*>(&s_basis[idx]);
                acc = __builtin_amdgcn_mfma_f32_16x16x32_bf16(a, Bfr[q], acc, 0, 0, 0);
            }
            const int row0 = row_base + t * 16 + h * 4;
#pragma unroll
            for (int i = 0; i < 4; ++i) {
                out[(size_t)(row0 + i) * C + cidx] = acc[i];
            }
        }

        if (mt + 1 < MT) {
#pragma unroll
            for (int m = 0; m < 8; ++m) xq[m] = xn[m];
        }
    }
}

extern "C" void kernel_launch(void* const* d_in, const int* in_sizes, int n_in,
                              void* d_out, int out_size, void* d_ws, size_t ws_size,
                              hipStream_t stream) {
    const float* X  = (const float*)d_in[0];
    const float* ph = (const float*)d_in[1];
    const float* lw = (const float*)d_in[2];
    const float* ss = (const float*)d_in[3];
    const float* sb = (const float*)d_in[4];
    const float* kc = (const float*)d_in[5];
    const float* kb = (const float*)d_in[6];
    float* out = (float*)d_out;
    qkan_kernel<<<dim3(NBLK), dim3(256), 0, stream>>>(X, ph, lw, ss, sb, kc, kb, out);
}